// Round 1
// baseline (4437.997 us; speedup 1.0000x reference)
//
#include <hip/hip_runtime.h>
#include <hip/hip_bf16.h>

typedef __attribute__((ext_vector_type(8))) short short8;
typedef __attribute__((ext_vector_type(4))) short short4v;
typedef __attribute__((ext_vector_type(4))) float floatx4;

#define B_SZ 2
#define S_SZ 2048
#define HS_SZ 4096
#define NH_SZ 32
#define HD_SZ 128
#define INTER_SZ 11008
#define M_TOT 4096

__device__ __forceinline__ float b2f(short s){
  unsigned int u = ((unsigned int)(unsigned short)s) << 16;
  return __builtin_bit_cast(float, u);
}
__device__ __forceinline__ short f2b(float f){
  unsigned int u = __builtin_bit_cast(unsigned int, f);
  u = (u + 0x7FFFu + ((u >> 16) & 1u)) >> 16;
  return (short)u;
}

// ---------------- embedding gather + concat -> X0 bf16 [M, 2*HS] ----------------
__global__ void embed_concat_kernel(const float* __restrict__ hidden,
                                    const int* __restrict__ ids,
                                    const float* __restrict__ embed,
                                    short* __restrict__ X0){
  long idx = (long)blockIdx.x * blockDim.x + threadIdx.x;
  const long total = (long)M_TOT * (2*HS_SZ) / 4;
  if (idx >= total) return;
  long e = idx * 4;
  int m = (int)(e / (2*HS_SZ));
  int c = (int)(e % (2*HS_SZ));
  const float* src;
  if (c < HS_SZ){
    src = embed + (long)ids[m]*HS_SZ + c;
  } else {
    src = hidden + (long)m*HS_SZ + (c - HS_SZ);
  }
  floatx4 v = *(const floatx4*)src;
  short4v o;
  o[0]=f2b(v[0]); o[1]=f2b(v[1]); o[2]=f2b(v[2]); o[3]=f2b(v[3]);
  *(short4v*)(X0 + e) = o;
}

// ---------------- NT GEMM: C[M,N] = A(bf16,[M,K]) * B(f32,[N,K])^T ----------------
// EPI 0: write bf16.  EPI 1: +bias, write bf16 AND f32.  EPI 2: +resid(f32), write f32.
template<int EPI>
__global__ __launch_bounds__(256,2)
void gemm_nt_kernel(const short* __restrict__ A, const float* __restrict__ Bw,
                    int M, int N, int K,
                    const float* __restrict__ bias,
                    const float* __restrict__ resid,
                    short* __restrict__ Cbf,
                    float* __restrict__ Cf){
  constexpr int BM=128, BN=128, BK=64, LDT=BK+8;
  __shared__ __align__(16) short a_lds[BM*LDT];
  __shared__ __align__(16) short b_lds[BN*LDT];
  const int tid = threadIdx.x;
  const int wid = tid >> 6;
  const int lane = tid & 63;
  const int wm = wid >> 1, wn = wid & 1;
  const int m0 = blockIdx.x * BM, n0 = blockIdx.y * BN;
  const int lr = lane & 15, lk = lane >> 4;
  floatx4 acc[4][4] = {};
  const int sr = tid >> 3;        // 0..31
  const int sc = (tid & 7) * 8;   // 0..56

  for (int k0 = 0; k0 < K; k0 += BK){
    #pragma unroll
    for (int p=0;p<4;p++){
      int row = sr + p*32;
      *(short8*)(a_lds + row*LDT + sc) = *(const short8*)(A + (long)(m0+row)*K + k0 + sc);
    }
    #pragma unroll
    for (int p=0;p<4;p++){
      int row = sr + p*32;
      const float* bp = Bw + (long)(n0+row)*K + k0 + sc;
      floatx4 v0 = *(const floatx4*)bp;
      floatx4 v1 = *(const floatx4*)(bp+4);
      short8 bv;
      bv[0]=f2b(v0[0]); bv[1]=f2b(v0[1]); bv[2]=f2b(v0[2]); bv[3]=f2b(v0[3]);
      bv[4]=f2b(v1[0]); bv[5]=f2b(v1[1]); bv[6]=f2b(v1[2]); bv[7]=f2b(v1[3]);
      *(short8*)(b_lds + row*LDT + sc) = bv;
    }
    __syncthreads();
    #pragma unroll
    for (int kk=0; kk<BK; kk+=32){
      short8 af[4], bfr[4];
      #pragma unroll
      for (int i=0;i<4;i++) af[i]  = *(const short8*)(a_lds + (wm*64 + i*16 + lr)*LDT + kk + lk*8);
      #pragma unroll
      for (int j=0;j<4;j++) bfr[j] = *(const short8*)(b_lds + (wn*64 + j*16 + lr)*LDT + kk + lk*8);
      #pragma unroll
      for (int i=0;i<4;i++)
        #pragma unroll
        for (int j=0;j<4;j++)
          acc[i][j] = __builtin_amdgcn_mfma_f32_16x16x32_bf16(af[i], bfr[j], acc[i][j], 0, 0, 0);
    }
    __syncthreads();
  }
  #pragma unroll
  for (int i=0;i<4;i++){
    #pragma unroll
    for (int j=0;j<4;j++){
      const int col = n0 + wn*64 + j*16 + lr;
      float bcol = (EPI==1) ? bias[col] : 0.0f;
      #pragma unroll
      for (int r=0;r<4;r++){
        const int row = m0 + wm*64 + i*16 + lk*4 + r;
        float v = acc[i][j][r] + bcol;
        if (EPI==2) v += resid[(long)row*N + col];
        if (EPI==0 || EPI==1) Cbf[(long)row*N + col] = f2b(v);
        if (EPI==1 || EPI==2) Cf[(long)row*N + col] = v;
      }
    }
  }
}

// ---------------- RoPE in-place on q,k bf16 [M, NH*HD] ----------------
__global__ void rope_kernel(short* __restrict__ q, short* __restrict__ k,
                            const int* __restrict__ pos_ids){
  long idx = (long)blockIdx.x * blockDim.x + threadIdx.x;
  const long total = (long)M_TOT * NH_SZ * (HD_SZ/2);
  if (idx >= total) return;
  int i  = (int)(idx & 63);       // rotary pair index 0..63
  long rh = idx >> 6;
  int h  = (int)(rh & 31);
  int m  = (int)(rh >> 5);
  int s  = m & (S_SZ - 1);
  float p = (float)pos_ids[s];
  const float L2_10000 = 13.28771237954945f;
  float inv = exp2f(-(2.0f*i/(float)HD_SZ) * L2_10000);
  float fr = p * inv;
  float sn, cs;
  sincosf(fr, &sn, &cs);
  long base = (long)m*HS_SZ + h*HD_SZ;
  short* qp = q + base;
  short* kp = k + base;
  float q1=b2f(qp[i]), q2=b2f(qp[i+64]);
  qp[i]    = f2b(q1*cs - q2*sn);
  qp[i+64] = f2b(q2*cs + q1*sn);
  float k1=b2f(kp[i]), k2=b2f(kp[i+64]);
  kp[i]    = f2b(k1*cs - k2*sn);
  kp[i+64] = f2b(k2*cs + k1*sn);
}

// ---------------- causal flash attention ----------------
// Q,K,V,O: bf16 [B, S, NH*HD].  grid: (S/64, B*NH). 4 waves, 16 q-rows each.
__global__ __launch_bounds__(256,2)
void attn_kernel(const short* __restrict__ Q, const short* __restrict__ K,
                 const short* __restrict__ V, short* __restrict__ O){
  constexpr int QB=64, KVB=32;
  constexpr int LKD = HD_SZ + 8;   // 136
  constexpr int LVD = KVB + 8;     // 40
  constexpr int LPD = KVB + 8;     // 40
  __shared__ __align__(16) short k_lds[KVB*LKD];
  __shared__ __align__(16) short vt_lds[HD_SZ*LVD];
  __shared__ __align__(16) short p_lds[4][16*LPD];
  const int bh = blockIdx.y;
  const int b = bh >> 5, h = bh & 31;
  const int q0 = blockIdx.x * QB;
  const int tid = threadIdx.x, wid = tid>>6, lane = tid&63;
  const int lr = lane & 15, lk = lane >> 4;
  const float scale = 0.08838834764831845f;  // 1/sqrt(128)

  // hoist Q fragments (A-operand): row=lr, k = t*32 + lk*8
  const short* qbase = Q + ((long)(b*S_SZ + q0 + wid*16))*HS_SZ + h*HD_SZ;
  short8 qf[4];
  #pragma unroll
  for (int t=0;t<4;t++)
    qf[t] = *(const short8*)(qbase + (long)lr*HS_SZ + t*32 + lk*8);

  floatx4 oacc[8] = {};
  float m_run[4] = {-1e30f,-1e30f,-1e30f,-1e30f};
  float l_run[4] = {0.f,0.f,0.f,0.f};

  const int kv_end = q0 + QB;      // causal bound
  const int sr_ = tid >> 3;        // 0..31
  const int sc_ = (tid & 7) * 16;  // 0..112

  for (int kv0 = 0; kv0 < kv_end; kv0 += KVB){
    // stage K [32][128] row-major and V^T [128][32]
    {
      const short* kp = K + ((long)(b*S_SZ + kv0 + sr_))*HS_SZ + h*HD_SZ + sc_;
      *(short8*)(k_lds + sr_*LKD + sc_)     = *(const short8*)kp;
      *(short8*)(k_lds + sr_*LKD + sc_ + 8) = *(const short8*)(kp + 8);
      const short* vp = V + ((long)(b*S_SZ + kv0 + sr_))*HS_SZ + h*HD_SZ + sc_;
      #pragma unroll
      for (int j=0;j<16;j++)
        vt_lds[(sc_+j)*LVD + sr_] = vp[j];
    }
    __syncthreads();
    // S = Q K^T (per wave: 16q x 32kv)
    floatx4 sfr[2];
    #pragma unroll
    for (int fn=0; fn<2; fn++){
      floatx4 s = {0.f,0.f,0.f,0.f};
      #pragma unroll
      for (int t=0;t<4;t++){
        short8 kf = *(const short8*)(k_lds + (fn*16+lr)*LKD + t*32 + lk*8);
        s = __builtin_amdgcn_mfma_f32_16x16x32_bf16(qf[t], kf, s, 0,0,0);
      }
      sfr[fn] = s;
    }
    // online softmax (rows owned per lane: lk*4+r; cols fn*16+lr)
    float pv[2][4];
    #pragma unroll
    for (int fn=0; fn<2; fn++){
      const int col = kv0 + fn*16 + lr;
      #pragma unroll
      for (int r=0;r<4;r++){
        const int row = q0 + wid*16 + lk*4 + r;
        float sv = sfr[fn][r] * scale;
        pv[fn][r] = (col > row) ? -1e30f : sv;
      }
    }
    float alpha_[4];
    #pragma unroll
    for (int r=0;r<4;r++){
      float mr = fmaxf(pv[0][r], pv[1][r]);
      mr = fmaxf(mr, __shfl_xor(mr, 1, 16));
      mr = fmaxf(mr, __shfl_xor(mr, 2, 16));
      mr = fmaxf(mr, __shfl_xor(mr, 4, 16));
      mr = fmaxf(mr, __shfl_xor(mr, 8, 16));
      float mnew = fmaxf(m_run[r], mr);
      float alpha = __expf(m_run[r] - mnew);
      float e0 = __expf(pv[0][r] - mnew);
      float e1 = __expf(pv[1][r] - mnew);
      p_lds[wid][(lk*4+r)*LPD + lr]      = f2b(e0);
      p_lds[wid][(lk*4+r)*LPD + 16 + lr] = f2b(e1);
      float rs = e0 + e1;
      rs += __shfl_xor(rs, 1, 16);
      rs += __shfl_xor(rs, 2, 16);
      rs += __shfl_xor(rs, 4, 16);
      rs += __shfl_xor(rs, 8, 16);
      l_run[r] = l_run[r]*alpha + rs;
      m_run[r] = mnew;
      alpha_[r] = alpha;
    }
    #pragma unroll
    for (int f=0; f<8; f++){
      #pragma unroll
      for (int r=0;r<4;r++) oacc[f][r] *= alpha_[r];
    }
    __syncthreads();
    // O += P V  (A-frag: row=lr q, k=lk*8 kv; B-frag from V^T)
    short8 pf = *(const short8*)(&p_lds[wid][lr*LPD + lk*8]);
    #pragma unroll
    for (int f=0; f<8; f++){
      short8 vf = *(const short8*)(vt_lds + (f*16+lr)*LVD + lk*8);
      oacc[f] = __builtin_amdgcn_mfma_f32_16x16x32_bf16(pf, vf, oacc[f], 0,0,0);
    }
    __syncthreads();
  }
  // normalize + write [B,S,NH*HD]
  #pragma unroll
  for (int r=0;r<4;r++){
    const float inv = 1.0f / l_run[r];
    const long row = (long)(b*S_SZ + q0 + wid*16 + lk*4 + r);
    #pragma unroll
    for (int f=0; f<8; f++){
      O[row*HS_SZ + h*HD_SZ + f*16 + lr] = f2b(oacc[f][r]*inv);
    }
  }
}

// ---------------- RMSNorm: f32 in -> bf16 out ----------------
__global__ void rmsnorm_kernel(const float* __restrict__ X, const float* __restrict__ W,
                               short* __restrict__ Y){
  const int row = blockIdx.x;
  const float* x = X + (long)row*HS_SZ;
  float ss = 0.f;
  for (int c = threadIdx.x*4; c < HS_SZ; c += 256*4){
    floatx4 v = *(const floatx4*)(x + c);
    ss += v[0]*v[0] + v[1]*v[1] + v[2]*v[2] + v[3]*v[3];
  }
  ss += __shfl_xor(ss, 32); ss += __shfl_xor(ss, 16);
  ss += __shfl_xor(ss, 8);  ss += __shfl_xor(ss, 4);
  ss += __shfl_xor(ss, 2);  ss += __shfl_xor(ss, 1);
  __shared__ float red[4];
  if ((threadIdx.x & 63) == 0) red[threadIdx.x >> 6] = ss;
  __syncthreads();
  ss = red[0] + red[1] + red[2] + red[3];
  const float rs = rsqrtf(ss / (float)HS_SZ + 1e-6f);
  for (int c = threadIdx.x*4; c < HS_SZ; c += 256*4){
    floatx4 v = *(const floatx4*)(x + c);
    floatx4 w = *(const floatx4*)(W + c);
    short4v o;
    o[0]=f2b(v[0]*rs*w[0]); o[1]=f2b(v[1]*rs*w[1]);
    o[2]=f2b(v[2]*rs*w[2]); o[3]=f2b(v[3]*rs*w[3]);
    *(short4v*)(Y + (long)row*HS_SZ + c) = o;
  }
}

// ---------------- act = silu(g) * u (in-place into g) ----------------
__global__ void silu_mul_kernel(short* __restrict__ G, const short* __restrict__ U){
  long idx = (long)blockIdx.x * blockDim.x + threadIdx.x;
  const long total = (long)M_TOT * INTER_SZ / 8;
  if (idx >= total) return;
  long e = idx * 8;
  short8 g = *(short8*)(G + e);
  short8 u = *(const short8*)(U + e);
  short8 o;
  #pragma unroll
  for (int j=0;j<8;j++){
    float gf = b2f(g[j]);
    float uf = b2f(u[j]);
    float s = gf / (1.0f + __expf(-gf));
    o[j] = f2b(s * uf);
  }
  *(short8*)(G + e) = o;
}

extern "C" void kernel_launch(void* const* d_in, const int* in_sizes, int n_in,
                              void* d_out, int out_size, void* d_ws, size_t ws_size,
                              hipStream_t stream){
  (void)in_sizes; (void)n_in; (void)out_size;
  const float* hidden = (const float*)d_in[0];
  const int*   ids    = (const int*)d_in[1];
  const int*   pos    = (const int*)d_in[2];
  const float* embed  = (const float*)d_in[3];
  const float* fc_w   = (const float*)d_in[4];
  const float* fc_b   = (const float*)d_in[5];
  const float* q_w    = (const float*)d_in[6];
  const float* k_w    = (const float*)d_in[7];
  const float* v_w    = (const float*)d_in[8];
  const float* o_w    = (const float*)d_in[9];
  const float* gate_w = (const float*)d_in[10];
  const float* up_w   = (const float*)d_in[11];
  const float* down_w = (const float*)d_in[12];
  const float* ln_w   = (const float*)d_in[13];

  char* ws = (char*)d_ws;
  size_t off = 0;
  auto alloc = [&](size_t bytes)->char*{
    char* p = ws + off;
    off = (off + bytes + 255) & ~(size_t)255;
    return p;
  };
  short* X0   = (short*)alloc((size_t)M_TOT*2*HS_SZ*2);
  short* h_bf = (short*)alloc((size_t)M_TOT*HS_SZ*2);
  float* h_f  = (float*)alloc((size_t)M_TOT*HS_SZ*4);
  short* q_bf = (short*)alloc((size_t)M_TOT*HS_SZ*2);
  short* k_bf = (short*)alloc((size_t)M_TOT*HS_SZ*2);
  short* v_bf = (short*)alloc((size_t)M_TOT*HS_SZ*2);
  short* a_bf = (short*)alloc((size_t)M_TOT*HS_SZ*2);
  float* h2_f = (float*)alloc((size_t)M_TOT*HS_SZ*4);
  short* hn_bf= (short*)alloc((size_t)M_TOT*HS_SZ*2);
  short* g_bf = (short*)alloc((size_t)M_TOT*INTER_SZ*2);
  short* u_bf = (short*)alloc((size_t)M_TOT*INTER_SZ*2);
  if (ws_size < off) return;  // insufficient workspace -> loud failure

  embed_concat_kernel<<<32768, 256, 0, stream>>>(hidden, ids, embed, X0);
  gemm_nt_kernel<1><<<dim3(32,32), 256, 0, stream>>>(X0, fc_w, M_TOT, HS_SZ, 2*HS_SZ,
                                                     fc_b, nullptr, h_bf, h_f);
  gemm_nt_kernel<0><<<dim3(32,32), 256, 0, stream>>>(h_bf, q_w, M_TOT, HS_SZ, HS_SZ,
                                                     nullptr, nullptr, q_bf, nullptr);
  gemm_nt_kernel<0><<<dim3(32,32), 256, 0, stream>>>(h_bf, k_w, M_TOT, HS_SZ, HS_SZ,
                                                     nullptr, nullptr, k_bf, nullptr);
  gemm_nt_kernel<0><<<dim3(32,32), 256, 0, stream>>>(h_bf, v_w, M_TOT, HS_SZ, HS_SZ,
                                                     nullptr, nullptr, v_bf, nullptr);
  rope_kernel<<<32768, 256, 0, stream>>>(q_bf, k_bf, pos);
  attn_kernel<<<dim3(S_SZ/64, B_SZ*NH_SZ), 256, 0, stream>>>(q_bf, k_bf, v_bf, a_bf);
  gemm_nt_kernel<2><<<dim3(32,32), 256, 0, stream>>>(a_bf, o_w, M_TOT, HS_SZ, HS_SZ,
                                                     nullptr, h_f, nullptr, h2_f);
  rmsnorm_kernel<<<M_TOT, 256, 0, stream>>>(h2_f, ln_w, hn_bf);
  gemm_nt_kernel<0><<<dim3(32,86), 256, 0, stream>>>(hn_bf, gate_w, M_TOT, INTER_SZ, HS_SZ,
                                                     nullptr, nullptr, g_bf, nullptr);
  gemm_nt_kernel<0><<<dim3(32,86), 256, 0, stream>>>(hn_bf, up_w, M_TOT, INTER_SZ, HS_SZ,
                                                     nullptr, nullptr, u_bf, nullptr);
  silu_mul_kernel<<<22016, 256, 0, stream>>>(g_bf, u_bf);
  gemm_nt_kernel<2><<<dim3(32,32), 256, 0, stream>>>(g_bf, down_w, M_TOT, HS_SZ, INTER_SZ,
                                                     nullptr, h2_f, nullptr, (float*)d_out);
}

// Round 2
// 3863.502 us; speedup vs baseline: 1.1487x; 1.1487x over previous
//
#include <hip/hip_runtime.h>
#include <hip/hip_bf16.h>

typedef __attribute__((ext_vector_type(8))) short short8;
typedef __attribute__((ext_vector_type(4))) short short4v;
typedef __attribute__((ext_vector_type(4))) float floatx4;

#define B_SZ 2
#define S_SZ 2048
#define HS_SZ 4096
#define NH_SZ 32
#define HD_SZ 128
#define INTER_SZ 11008
#define M_TOT 4096

__device__ __forceinline__ float b2f(short s){
  unsigned int u = ((unsigned int)(unsigned short)s) << 16;
  return __builtin_bit_cast(float, u);
}
__device__ __forceinline__ short f2b(float f){
  unsigned int u = __builtin_bit_cast(unsigned int, f);
  u = (u + 0x7FFFu + ((u >> 16) & 1u)) >> 16;
  return (short)u;
}

typedef __attribute__((address_space(1))) const unsigned int gu32;
typedef __attribute__((address_space(3))) unsigned int lu32;
__device__ __forceinline__ void gl2lds16(const short* g, short* l){
  __builtin_amdgcn_global_load_lds((gu32*)g, (lu32*)l, 16, 0, 0);
}

// ---------------- f32 -> bf16 convert (weights) ----------------
__global__ void cvt_bf16_kernel(const float* __restrict__ src, short* __restrict__ dst, long n8){
  long idx = (long)blockIdx.x * blockDim.x + threadIdx.x;
  if (idx >= n8) return;
  long e = idx * 8;
  floatx4 v0 = *(const floatx4*)(src + e);
  floatx4 v1 = *(const floatx4*)(src + e + 4);
  short8 o;
  o[0]=f2b(v0[0]); o[1]=f2b(v0[1]); o[2]=f2b(v0[2]); o[3]=f2b(v0[3]);
  o[4]=f2b(v1[0]); o[5]=f2b(v1[1]); o[6]=f2b(v1[2]); o[7]=f2b(v1[3]);
  *(short8*)(dst + e) = o;
}

// ---------------- embedding gather + concat -> X0 bf16 [M, 2*HS] ----------------
__global__ void embed_concat_kernel(const float* __restrict__ hidden,
                                    const int* __restrict__ ids,
                                    const float* __restrict__ embed,
                                    short* __restrict__ X0){
  long idx = (long)blockIdx.x * blockDim.x + threadIdx.x;
  const long total = (long)M_TOT * (2*HS_SZ) / 4;
  if (idx >= total) return;
  long e = idx * 4;
  int m = (int)(e / (2*HS_SZ));
  int c = (int)(e % (2*HS_SZ));
  const float* src;
  if (c < HS_SZ){
    src = embed + (long)ids[m]*HS_SZ + c;
  } else {
    src = hidden + (long)m*HS_SZ + (c - HS_SZ);
  }
  floatx4 v = *(const floatx4*)src;
  short4v o;
  o[0]=f2b(v[0]); o[1]=f2b(v[1]); o[2]=f2b(v[2]); o[3]=f2b(v[3]);
  *(short4v*)(X0 + e) = o;
}

// ---------------- NT GEMM (m97 structure): C[M,N] = A(bf16,[M,K]) * B(bf16,[N,K])^T
// 128x128 tile, BK=64, linear LDS, global_load_lds width-16, 4 waves 2x2, 4x4 frags.
// EPI 0: write bf16.  EPI 1: +bias, write bf16 AND f32.  EPI 2: +resid(f32), write f32.
template<int EPI>
__global__ __launch_bounds__(256)
void gemm_nt_kernel(const short* __restrict__ A, const short* __restrict__ Bw,
                    int M, int N, int K,
                    const float* __restrict__ bias,
                    const float* __restrict__ resid,
                    short* __restrict__ Cbf,
                    float* __restrict__ Cf){
  constexpr int BK = 64;
  __shared__ __align__(16) short a_lds[128*BK];
  __shared__ __align__(16) short b_lds[128*BK];
  const int tid = threadIdx.x;
  const int wid = tid >> 6;
  const int lane = tid & 63;
  const int wm = wid >> 1, wn = wid & 1;
  const int m0 = blockIdx.x * 128, n0 = blockIdx.y * 128;
  const int lr = lane & 15, lk = lane >> 4;
  floatx4 acc[4][4] = {};
  // staging geometry: inst = wid*4+p covers LDS bytes [inst*1024, inst*1024+1024)
  // lane l -> lds short offset inst*512 + l*8 -> row = inst*8 + l/8, col = (l%8)*8
  const int srow = (lane >> 3);        // 0..7 within inst
  const int scol = (lane & 7) * 8;     // shorts

  for (int k0 = 0; k0 < K; k0 += BK){
    #pragma unroll
    for (int p = 0; p < 4; p++){
      const int inst = wid*4 + p;
      const int row = inst*8 + srow;
      gl2lds16(A + (long)(m0+row)*K + k0 + scol, a_lds + inst*512);
      gl2lds16(Bw + (long)(n0+row)*K + k0 + scol, b_lds + inst*512);
    }
    __syncthreads();
    #pragma unroll
    for (int kk = 0; kk < BK; kk += 32){
      short8 af[4], bfr[4];
      #pragma unroll
      for (int i=0;i<4;i++) af[i]  = *(const short8*)(a_lds + (wm*64 + i*16 + lr)*BK + kk + lk*8);
      #pragma unroll
      for (int j=0;j<4;j++) bfr[j] = *(const short8*)(b_lds + (wn*64 + j*16 + lr)*BK + kk + lk*8);
      #pragma unroll
      for (int i=0;i<4;i++)
        #pragma unroll
        for (int j=0;j<4;j++)
          acc[i][j] = __builtin_amdgcn_mfma_f32_16x16x32_bf16(af[i], bfr[j], acc[i][j], 0, 0, 0);
    }
    __syncthreads();
  }
  #pragma unroll
  for (int i=0;i<4;i++){
    #pragma unroll
    for (int j=0;j<4;j++){
      const int col = n0 + wn*64 + j*16 + lr;
      float bcol = (EPI==1) ? bias[col] : 0.0f;
      #pragma unroll
      for (int r=0;r<4;r++){
        const int row = m0 + wm*64 + i*16 + lk*4 + r;
        float v = acc[i][j][r] + bcol;
        if (EPI==2) v += resid[(long)row*N + col];
        if (EPI==0 || EPI==1) Cbf[(long)row*N + col] = f2b(v);
        if (EPI==1 || EPI==2) Cf[(long)row*N + col] = v;
      }
    }
  }
}

// ---------------- RoPE in-place on q,k bf16 [M, NH*HD] ----------------
__global__ void rope_kernel(short* __restrict__ q, short* __restrict__ k,
                            const int* __restrict__ pos_ids){
  long idx = (long)blockIdx.x * blockDim.x + threadIdx.x;
  const long total = (long)M_TOT * NH_SZ * (HD_SZ/2);
  if (idx >= total) return;
  int i  = (int)(idx & 63);
  long rh = idx >> 6;
  int h  = (int)(rh & 31);
  int m  = (int)(rh >> 5);
  int s  = m & (S_SZ - 1);
  float p = (float)pos_ids[s];
  const float L2_10000 = 13.28771237954945f;
  float inv = exp2f(-(2.0f*i/(float)HD_SZ) * L2_10000);
  float fr = p * inv;
  float sn, cs;
  sincosf(fr, &sn, &cs);
  long base = (long)m*HS_SZ + h*HD_SZ;
  short* qp = q + base;
  short* kp = k + base;
  float q1=b2f(qp[i]), q2=b2f(qp[i+64]);
  qp[i]    = f2b(q1*cs - q2*sn);
  qp[i+64] = f2b(q2*cs + q1*sn);
  float k1=b2f(kp[i]), k2=b2f(kp[i+64]);
  kp[i]    = f2b(k1*cs - k2*sn);
  kp[i+64] = f2b(k2*cs + k1*sn);
}

// ---------------- causal flash attention ----------------
__global__ __launch_bounds__(256,2)
void attn_kernel(const short* __restrict__ Q, const short* __restrict__ K,
                 const short* __restrict__ V, short* __restrict__ O){
  constexpr int QB=64, KVB=32;
  constexpr int LKD = HD_SZ + 8;
  constexpr int LVD = KVB + 8;
  constexpr int LPD = KVB + 8;
  __shared__ __align__(16) short k_lds[KVB*LKD];
  __shared__ __align__(16) short vt_lds[HD_SZ*LVD];
  __shared__ __align__(16) short p_lds[4][16*LPD];
  const int bh = blockIdx.y;
  const int b = bh >> 5, h = bh & 31;
  const int q0 = blockIdx.x * QB;
  const int tid = threadIdx.x, wid = tid>>6, lane = tid&63;
  const int lr = lane & 15, lk = lane >> 4;
  const float scale = 0.08838834764831845f;

  const short* qbase = Q + ((long)(b*S_SZ + q0 + wid*16))*HS_SZ + h*HD_SZ;
  short8 qf[4];
  #pragma unroll
  for (int t=0;t<4;t++)
    qf[t] = *(const short8*)(qbase + (long)lr*HS_SZ + t*32 + lk*8);

  floatx4 oacc[8] = {};
  float m_run[4] = {-1e30f,-1e30f,-1e30f,-1e30f};
  float l_run[4] = {0.f,0.f,0.f,0.f};

  const int kv_end = q0 + QB;
  const int sr_ = tid >> 3;
  const int sc_ = (tid & 7) * 16;

  for (int kv0 = 0; kv0 < kv_end; kv0 += KVB){
    {
      const short* kp = K + ((long)(b*S_SZ + kv0 + sr_))*HS_SZ + h*HD_SZ + sc_;
      *(short8*)(k_lds + sr_*LKD + sc_)     = *(const short8*)kp;
      *(short8*)(k_lds + sr_*LKD + sc_ + 8) = *(const short8*)(kp + 8);
      const short* vp = V + ((long)(b*S_SZ + kv0 + sr_))*HS_SZ + h*HD_SZ + sc_;
      #pragma unroll
      for (int j=0;j<16;j++)
        vt_lds[(sc_+j)*LVD + sr_] = vp[j];
    }
    __syncthreads();
    floatx4 sfr[2];
    #pragma unroll
    for (int fn=0; fn<2; fn++){
      floatx4 s = {0.f,0.f,0.f,0.f};
      #pragma unroll
      for (int t=0;t<4;t++){
        short8 kf = *(const short8*)(k_lds + (fn*16+lr)*LKD + t*32 + lk*8);
        s = __builtin_amdgcn_mfma_f32_16x16x32_bf16(qf[t], kf, s, 0,0,0);
      }
      sfr[fn] = s;
    }
    float pv[2][4];
    #pragma unroll
    for (int fn=0; fn<2; fn++){
      const int col = kv0 + fn*16 + lr;
      #pragma unroll
      for (int r=0;r<4;r++){
        const int row = q0 + wid*16 + lk*4 + r;
        float sv = sfr[fn][r] * scale;
        pv[fn][r] = (col > row) ? -1e30f : sv;
      }
    }
    float alpha_[4];
    #pragma unroll
    for (int r=0;r<4;r++){
      float mr = fmaxf(pv[0][r], pv[1][r]);
      mr = fmaxf(mr, __shfl_xor(mr, 1, 16));
      mr = fmaxf(mr, __shfl_xor(mr, 2, 16));
      mr = fmaxf(mr, __shfl_xor(mr, 4, 16));
      mr = fmaxf(mr, __shfl_xor(mr, 8, 16));
      float mnew = fmaxf(m_run[r], mr);
      float alpha = __expf(m_run[r] - mnew);
      float e0 = __expf(pv[0][r] - mnew);
      float e1 = __expf(pv[1][r] - mnew);
      p_lds[wid][(lk*4+r)*LPD + lr]      = f2b(e0);
      p_lds[wid][(lk*4+r)*LPD + 16 + lr] = f2b(e1);
      float rs = e0 + e1;
      rs += __shfl_xor(rs, 1, 16);
      rs += __shfl_xor(rs, 2, 16);
      rs += __shfl_xor(rs, 4, 16);
      rs += __shfl_xor(rs, 8, 16);
      l_run[r] = l_run[r]*alpha + rs;
      m_run[r] = mnew;
      alpha_[r] = alpha;
    }
    #pragma unroll
    for (int f=0; f<8; f++){
      #pragma unroll
      for (int r=0;r<4;r++) oacc[f][r] *= alpha_[r];
    }
    __syncthreads();
    short8 pf = *(const short8*)(&p_lds[wid][lr*LPD + lk*8]);
    #pragma unroll
    for (int f=0; f<8; f++){
      short8 vf = *(const short8*)(vt_lds + (f*16+lr)*LVD + lk*8);
      oacc[f] = __builtin_amdgcn_mfma_f32_16x16x32_bf16(pf, vf, oacc[f], 0,0,0);
    }
    __syncthreads();
  }
  #pragma unroll
  for (int r=0;r<4;r++){
    const float inv = 1.0f / l_run[r];
    const long row = (long)(b*S_SZ + q0 + wid*16 + lk*4 + r);
    #pragma unroll
    for (int f=0; f<8; f++){
      O[row*HS_SZ + h*HD_SZ + f*16 + lr] = f2b(oacc[f][r]*inv);
    }
  }
}

// ---------------- RMSNorm: f32 in -> bf16 out ----------------
__global__ void rmsnorm_kernel(const float* __restrict__ X, const float* __restrict__ W,
                               short* __restrict__ Y){
  const int row = blockIdx.x;
  const float* x = X + (long)row*HS_SZ;
  float ss = 0.f;
  for (int c = threadIdx.x*4; c < HS_SZ; c += 256*4){
    floatx4 v = *(const floatx4*)(x + c);
    ss += v[0]*v[0] + v[1]*v[1] + v[2]*v[2] + v[3]*v[3];
  }
  ss += __shfl_xor(ss, 32); ss += __shfl_xor(ss, 16);
  ss += __shfl_xor(ss, 8);  ss += __shfl_xor(ss, 4);
  ss += __shfl_xor(ss, 2);  ss += __shfl_xor(ss, 1);
  __shared__ float red[4];
  if ((threadIdx.x & 63) == 0) red[threadIdx.x >> 6] = ss;
  __syncthreads();
  ss = red[0] + red[1] + red[2] + red[3];
  const float rs = rsqrtf(ss / (float)HS_SZ + 1e-6f);
  for (int c = threadIdx.x*4; c < HS_SZ; c += 256*4){
    floatx4 v = *(const floatx4*)(x + c);
    floatx4 w = *(const floatx4*)(W + c);
    short4v o;
    o[0]=f2b(v[0]*rs*w[0]); o[1]=f2b(v[1]*rs*w[1]);
    o[2]=f2b(v[2]*rs*w[2]); o[3]=f2b(v[3]*rs*w[3]);
    *(short4v*)(Y + (long)row*HS_SZ + c) = o;
  }
}

// ---------------- act = silu(g) * u (in-place into g) ----------------
__global__ void silu_mul_kernel(short* __restrict__ G, const short* __restrict__ U){
  long idx = (long)blockIdx.x * blockDim.x + threadIdx.x;
  const long total = (long)M_TOT * INTER_SZ / 8;
  if (idx >= total) return;
  long e = idx * 8;
  short8 g = *(short8*)(G + e);
  short8 u = *(const short8*)(U + e);
  short8 o;
  #pragma unroll
  for (int j=0;j<8;j++){
    float gf = b2f(g[j]);
    float uf = b2f(u[j]);
    float s = gf / (1.0f + __expf(-gf));
    o[j] = f2b(s * uf);
  }
  *(short8*)(G + e) = o;
}

extern "C" void kernel_launch(void* const* d_in, const int* in_sizes, int n_in,
                              void* d_out, int out_size, void* d_ws, size_t ws_size,
                              hipStream_t stream){
  (void)in_sizes; (void)n_in; (void)out_size;
  const float* hidden = (const float*)d_in[0];
  const int*   ids    = (const int*)d_in[1];
  const int*   pos    = (const int*)d_in[2];
  const float* embed  = (const float*)d_in[3];
  const float* fc_w   = (const float*)d_in[4];
  const float* fc_b   = (const float*)d_in[5];
  const float* q_w    = (const float*)d_in[6];
  const float* k_w    = (const float*)d_in[7];
  const float* v_w    = (const float*)d_in[8];
  const float* o_w    = (const float*)d_in[9];
  const float* gate_w = (const float*)d_in[10];
  const float* up_w   = (const float*)d_in[11];
  const float* down_w = (const float*)d_in[12];
  const float* ln_w   = (const float*)d_in[13];

  char* ws = (char*)d_ws;
  size_t off = 0;
  auto alloc = [&](size_t bytes)->char*{
    char* p = ws + off;
    off = (off + bytes + 255) & ~(size_t)255;
    return p;
  };
  short* wbf  = (short*)alloc((size_t)INTER_SZ*HS_SZ*2);   // shared weight scratch (90 MB)
  short* X0   = (short*)alloc((size_t)M_TOT*2*HS_SZ*2);
  short* h_bf = (short*)alloc((size_t)M_TOT*HS_SZ*2);
  float* h_f  = (float*)alloc((size_t)M_TOT*HS_SZ*4);
  short* q_bf = (short*)alloc((size_t)M_TOT*HS_SZ*2);
  short* k_bf = (short*)alloc((size_t)M_TOT*HS_SZ*2);
  short* v_bf = (short*)alloc((size_t)M_TOT*HS_SZ*2);
  short* a_bf = (short*)alloc((size_t)M_TOT*HS_SZ*2);
  float* h2_f = (float*)alloc((size_t)M_TOT*HS_SZ*4);
  short* hn_bf= (short*)alloc((size_t)M_TOT*HS_SZ*2);
  short* g_bf = (short*)alloc((size_t)M_TOT*INTER_SZ*2);
  short* u_bf = (short*)alloc((size_t)M_TOT*INTER_SZ*2);
  if (ws_size < off) return;

  auto cvt = [&](const float* src, short* dst, long n){
    long n8 = n / 8;
    cvt_bf16_kernel<<<(int)((n8 + 255)/256), 256, 0, stream>>>(src, dst, n8);
  };

  embed_concat_kernel<<<32768, 256, 0, stream>>>(hidden, ids, embed, X0);

  cvt(fc_w, wbf, (long)HS_SZ*2*HS_SZ);
  gemm_nt_kernel<1><<<dim3(32,32), 256, 0, stream>>>(X0, wbf, M_TOT, HS_SZ, 2*HS_SZ,
                                                     fc_b, nullptr, h_bf, h_f);
  cvt(q_w, wbf, (long)HS_SZ*HS_SZ);
  gemm_nt_kernel<0><<<dim3(32,32), 256, 0, stream>>>(h_bf, wbf, M_TOT, HS_SZ, HS_SZ,
                                                     nullptr, nullptr, q_bf, nullptr);
  cvt(k_w, wbf, (long)HS_SZ*HS_SZ);
  gemm_nt_kernel<0><<<dim3(32,32), 256, 0, stream>>>(h_bf, wbf, M_TOT, HS_SZ, HS_SZ,
                                                     nullptr, nullptr, k_bf, nullptr);
  cvt(v_w, wbf, (long)HS_SZ*HS_SZ);
  gemm_nt_kernel<0><<<dim3(32,32), 256, 0, stream>>>(h_bf, wbf, M_TOT, HS_SZ, HS_SZ,
                                                     nullptr, nullptr, v_bf, nullptr);
  rope_kernel<<<32768, 256, 0, stream>>>(q_bf, k_bf, pos);
  attn_kernel<<<dim3(S_SZ/64, B_SZ*NH_SZ), 256, 0, stream>>>(q_bf, k_bf, v_bf, a_bf);
  cvt(o_w, wbf, (long)HS_SZ*HS_SZ);
  gemm_nt_kernel<2><<<dim3(32,32), 256, 0, stream>>>(a_bf, wbf, M_TOT, HS_SZ, HS_SZ,
                                                     nullptr, h_f, nullptr, h2_f);
  rmsnorm_kernel<<<M_TOT, 256, 0, stream>>>(h2_f, ln_w, hn_bf);
  cvt(gate_w, wbf, (long)INTER_SZ*HS_SZ);
  gemm_nt_kernel<0><<<dim3(32,86), 256, 0, stream>>>(hn_bf, wbf, M_TOT, INTER_SZ, HS_SZ,
                                                     nullptr, nullptr, g_bf, nullptr);
  cvt(up_w, wbf, (long)INTER_SZ*HS_SZ);
  gemm_nt_kernel<0><<<dim3(32,86), 256, 0, stream>>>(hn_bf, wbf, M_TOT, INTER_SZ, HS_SZ,
                                                     nullptr, nullptr, u_bf, nullptr);
  silu_mul_kernel<<<22016, 256, 0, stream>>>(g_bf, u_bf);
  cvt(down_w, wbf, (long)HS_SZ*INTER_SZ);
  gemm_nt_kernel<2><<<dim3(32,32), 256, 0, stream>>>(g_bf, wbf, M_TOT, HS_SZ, INTER_SZ,
                                                     nullptr, h2_f, nullptr, (float*)d_out);
}

// Round 3
// 2831.292 us; speedup vs baseline: 1.5675x; 1.3646x over previous
//
#include <hip/hip_runtime.h>
#include <hip/hip_bf16.h>

typedef __attribute__((ext_vector_type(8))) short short8;
typedef __attribute__((ext_vector_type(4))) short short4v;
typedef __attribute__((ext_vector_type(4))) float floatx4;

#define B_SZ 2
#define S_SZ 2048
#define HS_SZ 4096
#define NH_SZ 32
#define HD_SZ 128
#define INTER_SZ 11008
#define M_TOT 4096

__device__ __forceinline__ float b2f(short s){
  unsigned int u = ((unsigned int)(unsigned short)s) << 16;
  return __builtin_bit_cast(float, u);
}
__device__ __forceinline__ short f2b(float f){
  unsigned int u = __builtin_bit_cast(unsigned int, f);
  u = (u + 0x7FFFu + ((u >> 16) & 1u)) >> 16;
  return (short)u;
}

typedef __attribute__((address_space(1))) const unsigned int gu32;
typedef __attribute__((address_space(3))) unsigned int lu32;
__device__ __forceinline__ void gl2lds16(const short* g, short* l){
  __builtin_amdgcn_global_load_lds((gu32*)g, (lu32*)l, 16, 0, 0);
}

#define BARRIER() asm volatile("s_barrier" ::: "memory")
#define WAITV8()  asm volatile("s_waitcnt vmcnt(8)" ::: "memory")
#define WAITV0()  asm volatile("s_waitcnt vmcnt(0)" ::: "memory")

// ---------------- f32 -> bf16 convert (weights) ----------------
__global__ void cvt_bf16_kernel(const float* __restrict__ src, short* __restrict__ dst, long n8){
  long idx = (long)blockIdx.x * blockDim.x + threadIdx.x;
  if (idx >= n8) return;
  long e = idx * 8;
  floatx4 v0 = *(const floatx4*)(src + e);
  floatx4 v1 = *(const floatx4*)(src + e + 4);
  short8 o;
  o[0]=f2b(v0[0]); o[1]=f2b(v0[1]); o[2]=f2b(v0[2]); o[3]=f2b(v0[3]);
  o[4]=f2b(v1[0]); o[5]=f2b(v1[1]); o[6]=f2b(v1[2]); o[7]=f2b(v1[3]);
  *(short8*)(dst + e) = o;
}

// ---------------- embedding gather + concat -> X0 bf16 [M, 2*HS] ----------------
__global__ void embed_concat_kernel(const float* __restrict__ hidden,
                                    const int* __restrict__ ids,
                                    const float* __restrict__ embed,
                                    short* __restrict__ X0){
  long idx = (long)blockIdx.x * blockDim.x + threadIdx.x;
  const long total = (long)M_TOT * (2*HS_SZ) / 4;
  if (idx >= total) return;
  long e = idx * 4;
  int m = (int)(e / (2*HS_SZ));
  int c = (int)(e % (2*HS_SZ));
  const float* src;
  if (c < HS_SZ){
    src = embed + (long)ids[m]*HS_SZ + c;
  } else {
    src = hidden + (long)m*HS_SZ + (c - HS_SZ);
  }
  floatx4 v = *(const floatx4*)src;
  short4v o;
  o[0]=f2b(v[0]); o[1]=f2b(v[1]); o[2]=f2b(v[2]); o[3]=f2b(v[3]);
  *(short4v*)(X0 + e) = o;
}

// ---------------- 256x256 deep-pipelined NT GEMM ----------------
// C[M,N] = A(bf16,[M,K]) * B(bf16,[N,K])^T.  512 thr = 8 waves (2Mx4N),
// per-wave 128x64 out (acc[8][4]).  BK=64.  LDS 128 KiB double-buffered.
// Staging: global_load_lds w=16, pre-swizzled source (slot ^= row&7) so
// swizzled ds_read_b128 is bank-conflict-free.  Counted vmcnt(8), raw
// s_barrier x2 per K-tile, setprio around MFMA quadrants.
// EPI 0: bf16.  EPI 1: +bias -> bf16 AND f32.  EPI 2: +resid -> f32.
template<int EPI>
__global__ __launch_bounds__(512, 2)
void gemm256_kernel(const short* __restrict__ A, const short* __restrict__ Bw,
                    int M, int N, int K,
                    const float* __restrict__ bias,
                    const float* __restrict__ resid,
                    short* __restrict__ Cbf,
                    float* __restrict__ Cf){
  __shared__ __align__(16) short lds[65536];   // 128 KiB: [2 dbuf][A|B][256*64]
  const int tid = threadIdx.x;
  const int wid = tid >> 6;
  const int lane = tid & 63;
  const int wr = wid >> 2, wc = wid & 3;       // 2 x 4 wave grid
  const int lr = lane & 15, lk = lane >> 4;
  const int lr7 = lr & 7;

  // XCD-aware swizzle (all grids divisible by 8)
  const int nwg = gridDim.x * gridDim.y;
  const int id  = blockIdx.y * gridDim.x + blockIdx.x;
  const int cpx = nwg >> 3;
  const int sw  = (id & 7) * cpx + (id >> 3);
  const int bx  = sw % gridDim.x;              // M-tile
  const int by  = sw / gridDim.x;              // N-tile
  const int m0 = bx * 256, n0 = by * 256;

  // staging geometry: per (op,h,i): seg = wid*2+i (16 segs of 8 rows), lane
  // covers row seg*8 + lane/8, source col-slot = (lane&7) ^ (row&7)
  const int srow = lane >> 3;                  // 0..7, also row&7
  const int sslot = (lane & 7) ^ srow;         // pre-swizzled source slot
  const short* gsrc[8];
  int ldsoff[8];
  #pragma unroll
  for (int op=0; op<2; op++)
    #pragma unroll
    for (int h=0; h<2; h++)
      #pragma unroll
      for (int i=0; i<2; i++){
        const int u = op*4 + h*2 + i;
        const int seg = wid*2 + i;
        const int row = (op ? n0 : m0) + h*128 + seg*8 + srow;
        gsrc[u] = (op ? Bw : A) + (long)row*K + sslot*8;
        ldsoff[u] = op*16384 + h*8192 + seg*512;
      }

  floatx4 acc[8][4] = {};
  int a_base[8], b_base[4];
  #pragma unroll
  for (int mf=0; mf<8; mf++) a_base[mf] = (wr*128 + mf*16 + lr)*64;
  #pragma unroll
  for (int nf=0; nf<4; nf++) b_base[nf] = 16384 + (wc*64 + nf*16 + lr)*64;
  const int kslot[2] = { ((0*4+lk)^lr7)*8, ((1*4+lk)^lr7)*8 };

  const int nt = K >> 6;   // K / 64

  // prologue: stage tile 0 into buf 0
  #pragma unroll
  for (int u=0; u<8; u++) gl2lds16(gsrc[u], lds + ldsoff[u]);

  for (int t=0; t<nt; ++t){
    const int dbase = (t & 1) * 32768;
    const int nbase = ((t+1) & 1) * 32768;
    if (t+1 < nt){
      const long kn = (long)(t+1) * 64;
      #pragma unroll
      for (int u=0; u<8; u++) gl2lds16(gsrc[u] + kn, lds + nbase + ldsoff[u]);
      WAITV8();
    } else {
      WAITV0();
    }
    BARRIER();
    short8 bfr[4][2];
    #pragma unroll
    for (int q=0; q<4; q++){
      short8 af[2][2];
      #pragma unroll
      for (int p=0; p<2; p++){
        const int ab = dbase + a_base[q*2+p];
        af[p][0] = *(const short8*)(lds + ab + kslot[0]);
        af[p][1] = *(const short8*)(lds + ab + kslot[1]);
      }
      if (q == 0){
        #pragma unroll
        for (int nf=0; nf<4; nf++){
          const int bb = dbase + b_base[nf];
          bfr[nf][0] = *(const short8*)(lds + bb + kslot[0]);
          bfr[nf][1] = *(const short8*)(lds + bb + kslot[1]);
        }
      }
      __builtin_amdgcn_s_setprio(1);
      #pragma unroll
      for (int p=0; p<2; p++){
        #pragma unroll
        for (int nf=0; nf<4; nf++){
          acc[q*2+p][nf] = __builtin_amdgcn_mfma_f32_16x16x32_bf16(af[p][0], bfr[nf][0], acc[q*2+p][nf], 0,0,0);
          acc[q*2+p][nf] = __builtin_amdgcn_mfma_f32_16x16x32_bf16(af[p][1], bfr[nf][1], acc[q*2+p][nf], 0,0,0);
        }
      }
      __builtin_amdgcn_s_setprio(0);
    }
    BARRIER();
  }

  // epilogue
  #pragma unroll
  for (int mf=0; mf<8; mf++){
    #pragma unroll
    for (int nf=0; nf<4; nf++){
      const int col = n0 + wc*64 + nf*16 + lr;
      float bcol = (EPI==1) ? bias[col] : 0.0f;
      #pragma unroll
      for (int r=0; r<4; r++){
        const int row = m0 + wr*128 + mf*16 + lk*4 + r;
        float v = acc[mf][nf][r] + bcol;
        if (EPI==2) v += resid[(long)row*N + col];
        if (EPI==0 || EPI==1) Cbf[(long)row*N + col] = f2b(v);
        if (EPI==1 || EPI==2) Cf[(long)row*N + col] = v;
      }
    }
  }
}

// ---------------- RoPE in-place on q,k bf16 [M, NH*HD] ----------------
__global__ void rope_kernel(short* __restrict__ q, short* __restrict__ k,
                            const int* __restrict__ pos_ids){
  long idx = (long)blockIdx.x * blockDim.x + threadIdx.x;
  const long total = (long)M_TOT * NH_SZ * (HD_SZ/2);
  if (idx >= total) return;
  int i  = (int)(idx & 63);
  long rh = idx >> 6;
  int h  = (int)(rh & 31);
  int m  = (int)(rh >> 5);
  int s  = m & (S_SZ - 1);
  float p = (float)pos_ids[s];
  const float L2_10000 = 13.28771237954945f;
  float inv = exp2f(-(2.0f*i/(float)HD_SZ) * L2_10000);
  float fr = p * inv;
  float sn, cs;
  sincosf(fr, &sn, &cs);
  long base = (long)m*HS_SZ + h*HD_SZ;
  short* qp = q + base;
  short* kp = k + base;
  float q1=b2f(qp[i]), q2=b2f(qp[i+64]);
  qp[i]    = f2b(q1*cs - q2*sn);
  qp[i+64] = f2b(q2*cs + q1*sn);
  float k1=b2f(kp[i]), k2=b2f(kp[i+64]);
  kp[i]    = f2b(k1*cs - k2*sn);
  kp[i+64] = f2b(k2*cs + k1*sn);
}

// ---------------- causal flash attention (unchanged this round) ----------------
__global__ __launch_bounds__(256,2)
void attn_kernel(const short* __restrict__ Q, const short* __restrict__ K,
                 const short* __restrict__ V, short* __restrict__ O){
  constexpr int QB=64, KVB=32;
  constexpr int LKD = HD_SZ + 8;
  constexpr int LVD = KVB + 8;
  constexpr int LPD = KVB + 8;
  __shared__ __align__(16) short k_lds[KVB*LKD];
  __shared__ __align__(16) short vt_lds[HD_SZ*LVD];
  __shared__ __align__(16) short p_lds[4][16*LPD];
  const int bh = blockIdx.y;
  const int b = bh >> 5, h = bh & 31;
  const int q0 = blockIdx.x * QB;
  const int tid = threadIdx.x, wid = tid>>6, lane = tid&63;
  const int lr = lane & 15, lk = lane >> 4;
  const float scale = 0.08838834764831845f;

  const short* qbase = Q + ((long)(b*S_SZ + q0 + wid*16))*HS_SZ + h*HD_SZ;
  short8 qf[4];
  #pragma unroll
  for (int t=0;t<4;t++)
    qf[t] = *(const short8*)(qbase + (long)lr*HS_SZ + t*32 + lk*8);

  floatx4 oacc[8] = {};
  float m_run[4] = {-1e30f,-1e30f,-1e30f,-1e30f};
  float l_run[4] = {0.f,0.f,0.f,0.f};

  const int kv_end = q0 + QB;
  const int sr_ = tid >> 3;
  const int sc_ = (tid & 7) * 16;

  for (int kv0 = 0; kv0 < kv_end; kv0 += KVB){
    {
      const short* kp = K + ((long)(b*S_SZ + kv0 + sr_))*HS_SZ + h*HD_SZ + sc_;
      *(short8*)(k_lds + sr_*LKD + sc_)     = *(const short8*)kp;
      *(short8*)(k_lds + sr_*LKD + sc_ + 8) = *(const short8*)(kp + 8);
      const short* vp = V + ((long)(b*S_SZ + kv0 + sr_))*HS_SZ + h*HD_SZ + sc_;
      #pragma unroll
      for (int j=0;j<16;j++)
        vt_lds[(sc_+j)*LVD + sr_] = vp[j];
    }
    __syncthreads();
    floatx4 sfr[2];
    #pragma unroll
    for (int fn=0; fn<2; fn++){
      floatx4 s = {0.f,0.f,0.f,0.f};
      #pragma unroll
      for (int t=0;t<4;t++){
        short8 kf = *(const short8*)(k_lds + (fn*16+lr)*LKD + t*32 + lk*8);
        s = __builtin_amdgcn_mfma_f32_16x16x32_bf16(qf[t], kf, s, 0,0,0);
      }
      sfr[fn] = s;
    }
    float pv[2][4];
    #pragma unroll
    for (int fn=0; fn<2; fn++){
      const int col = kv0 + fn*16 + lr;
      #pragma unroll
      for (int r=0;r<4;r++){
        const int row = q0 + wid*16 + lk*4 + r;
        float sv = sfr[fn][r] * scale;
        pv[fn][r] = (col > row) ? -1e30f : sv;
      }
    }
    float alpha_[4];
    #pragma unroll
    for (int r=0;r<4;r++){
      float mr = fmaxf(pv[0][r], pv[1][r]);
      mr = fmaxf(mr, __shfl_xor(mr, 1, 16));
      mr = fmaxf(mr, __shfl_xor(mr, 2, 16));
      mr = fmaxf(mr, __shfl_xor(mr, 4, 16));
      mr = fmaxf(mr, __shfl_xor(mr, 8, 16));
      float mnew = fmaxf(m_run[r], mr);
      float alpha = __expf(m_run[r] - mnew);
      float e0 = __expf(pv[0][r] - mnew);
      float e1 = __expf(pv[1][r] - mnew);
      p_lds[wid][(lk*4+r)*LPD + lr]      = f2b(e0);
      p_lds[wid][(lk*4+r)*LPD + 16 + lr] = f2b(e1);
      float rs = e0 + e1;
      rs += __shfl_xor(rs, 1, 16);
      rs += __shfl_xor(rs, 2, 16);
      rs += __shfl_xor(rs, 4, 16);
      rs += __shfl_xor(rs, 8, 16);
      l_run[r] = l_run[r]*alpha + rs;
      m_run[r] = mnew;
      alpha_[r] = alpha;
    }
    #pragma unroll
    for (int f=0; f<8; f++){
      #pragma unroll
      for (int r=0;r<4;r++) oacc[f][r] *= alpha_[r];
    }
    __syncthreads();
    short8 pf = *(const short8*)(&p_lds[wid][lr*LPD + lk*8]);
    #pragma unroll
    for (int f=0; f<8; f++){
      short8 vf = *(const short8*)(vt_lds + (f*16+lr)*LVD + lk*8);
      oacc[f] = __builtin_amdgcn_mfma_f32_16x16x32_bf16(pf, vf, oacc[f], 0,0,0);
    }
    __syncthreads();
  }
  #pragma unroll
  for (int r=0;r<4;r++){
    const float inv = 1.0f / l_run[r];
    const long row = (long)(b*S_SZ + q0 + wid*16 + lk*4 + r);
    #pragma unroll
    for (int f=0; f<8; f++){
      O[row*HS_SZ + h*HD_SZ + f*16 + lr] = f2b(oacc[f][r]*inv);
    }
  }
}

// ---------------- RMSNorm: f32 in -> bf16 out ----------------
__global__ void rmsnorm_kernel(const float* __restrict__ X, const float* __restrict__ W,
                               short* __restrict__ Y){
  const int row = blockIdx.x;
  const float* x = X + (long)row*HS_SZ;
  float ss = 0.f;
  for (int c = threadIdx.x*4; c < HS_SZ; c += 256*4){
    floatx4 v = *(const floatx4*)(x + c);
    ss += v[0]*v[0] + v[1]*v[1] + v[2]*v[2] + v[3]*v[3];
  }
  ss += __shfl_xor(ss, 32); ss += __shfl_xor(ss, 16);
  ss += __shfl_xor(ss, 8);  ss += __shfl_xor(ss, 4);
  ss += __shfl_xor(ss, 2);  ss += __shfl_xor(ss, 1);
  __shared__ float red[4];
  if ((threadIdx.x & 63) == 0) red[threadIdx.x >> 6] = ss;
  __syncthreads();
  ss = red[0] + red[1] + red[2] + red[3];
  const float rs = rsqrtf(ss / (float)HS_SZ + 1e-6f);
  for (int c = threadIdx.x*4; c < HS_SZ; c += 256*4){
    floatx4 v = *(const floatx4*)(x + c);
    floatx4 w = *(const floatx4*)(W + c);
    short4v o;
    o[0]=f2b(v[0]*rs*w[0]); o[1]=f2b(v[1]*rs*w[1]);
    o[2]=f2b(v[2]*rs*w[2]); o[3]=f2b(v[3]*rs*w[3]);
    *(short4v*)(Y + (long)row*HS_SZ + c) = o;
  }
}

// ---------------- act = silu(g) * u (in-place into g) ----------------
__global__ void silu_mul_kernel(short* __restrict__ G, const short* __restrict__ U){
  long idx = (long)blockIdx.x * blockDim.x + threadIdx.x;
  const long total = (long)M_TOT * INTER_SZ / 8;
  if (idx >= total) return;
  long e = idx * 8;
  short8 g = *(short8*)(G + e);
  short8 u = *(const short8*)(U + e);
  short8 o;
  #pragma unroll
  for (int j=0;j<8;j++){
    float gf = b2f(g[j]);
    float uf = b2f(u[j]);
    float s = gf / (1.0f + __expf(-gf));
    o[j] = f2b(s * uf);
  }
  *(short8*)(G + e) = o;
}

extern "C" void kernel_launch(void* const* d_in, const int* in_sizes, int n_in,
                              void* d_out, int out_size, void* d_ws, size_t ws_size,
                              hipStream_t stream){
  (void)in_sizes; (void)n_in; (void)out_size;
  const float* hidden = (const float*)d_in[0];
  const int*   ids    = (const int*)d_in[1];
  const int*   pos    = (const int*)d_in[2];
  const float* embed  = (const float*)d_in[3];
  const float* fc_w   = (const float*)d_in[4];
  const float* fc_b   = (const float*)d_in[5];
  const float* q_w    = (const float*)d_in[6];
  const float* k_w    = (const float*)d_in[7];
  const float* v_w    = (const float*)d_in[8];
  const float* o_w    = (const float*)d_in[9];
  const float* gate_w = (const float*)d_in[10];
  const float* up_w   = (const float*)d_in[11];
  const float* down_w = (const float*)d_in[12];
  const float* ln_w   = (const float*)d_in[13];

  char* ws = (char*)d_ws;
  size_t off = 0;
  auto alloc = [&](size_t bytes)->char*{
    char* p = ws + off;
    off = (off + bytes + 255) & ~(size_t)255;
    return p;
  };
  short* wbf  = (short*)alloc((size_t)INTER_SZ*HS_SZ*2);   // shared weight scratch (90 MB)
  short* X0   = (short*)alloc((size_t)M_TOT*2*HS_SZ*2);
  short* h_bf = (short*)alloc((size_t)M_TOT*HS_SZ*2);
  float* h_f  = (float*)alloc((size_t)M_TOT*HS_SZ*4);
  short* q_bf = (short*)alloc((size_t)M_TOT*HS_SZ*2);
  short* k_bf = (short*)alloc((size_t)M_TOT*HS_SZ*2);
  short* v_bf = (short*)alloc((size_t)M_TOT*HS_SZ*2);
  short* a_bf = (short*)alloc((size_t)M_TOT*HS_SZ*2);
  float* h2_f = (float*)alloc((size_t)M_TOT*HS_SZ*4);
  short* hn_bf= (short*)alloc((size_t)M_TOT*HS_SZ*2);
  short* g_bf = (short*)alloc((size_t)M_TOT*INTER_SZ*2);
  short* u_bf = (short*)alloc((size_t)M_TOT*INTER_SZ*2);
  if (ws_size < off) return;

  auto cvt = [&](const float* src, short* dst, long n){
    long n8 = n / 8;
    cvt_bf16_kernel<<<(int)((n8 + 255)/256), 256, 0, stream>>>(src, dst, n8);
  };

  embed_concat_kernel<<<32768, 256, 0, stream>>>(hidden, ids, embed, X0);

  cvt(fc_w, wbf, (long)HS_SZ*2*HS_SZ);
  gemm256_kernel<1><<<dim3(16,16), 512, 0, stream>>>(X0, wbf, M_TOT, HS_SZ, 2*HS_SZ,
                                                     fc_b, nullptr, h_bf, h_f);
  cvt(q_w, wbf, (long)HS_SZ*HS_SZ);
  gemm256_kernel<0><<<dim3(16,16), 512, 0, stream>>>(h_bf, wbf, M_TOT, HS_SZ, HS_SZ,
                                                     nullptr, nullptr, q_bf, nullptr);
  cvt(k_w, wbf, (long)HS_SZ*HS_SZ);
  gemm256_kernel<0><<<dim3(16,16), 512, 0, stream>>>(h_bf, wbf, M_TOT, HS_SZ, HS_SZ,
                                                     nullptr, nullptr, k_bf, nullptr);
  cvt(v_w, wbf, (long)HS_SZ*HS_SZ);
  gemm256_kernel<0><<<dim3(16,16), 512, 0, stream>>>(h_bf, wbf, M_TOT, HS_SZ, HS_SZ,
                                                     nullptr, nullptr, v_bf, nullptr);
  rope_kernel<<<32768, 256, 0, stream>>>(q_bf, k_bf, pos);
  attn_kernel<<<dim3(S_SZ/64, B_SZ*NH_SZ), 256, 0, stream>>>(q_bf, k_bf, v_bf, a_bf);
  cvt(o_w, wbf, (long)HS_SZ*HS_SZ);
  gemm256_kernel<2><<<dim3(16,16), 512, 0, stream>>>(a_bf, wbf, M_TOT, HS_SZ, HS_SZ,
                                                     nullptr, h_f, nullptr, h2_f);
  rmsnorm_kernel<<<M_TOT, 256, 0, stream>>>(h2_f, ln_w, hn_bf);
  cvt(gate_w, wbf, (long)INTER_SZ*HS_SZ);
  gemm256_kernel<0><<<dim3(16,43), 512, 0, stream>>>(hn_bf, wbf, M_TOT, INTER_SZ, HS_SZ,
                                                     nullptr, nullptr, g_bf, nullptr);
  cvt(up_w, wbf, (long)INTER_SZ*HS_SZ);
  gemm256_kernel<0><<<dim3(16,43), 512, 0, stream>>>(hn_bf, wbf, M_TOT, INTER_SZ, HS_SZ,
                                                     nullptr, nullptr, u_bf, nullptr);
  silu_mul_kernel<<<22016, 256, 0, stream>>>(g_bf, u_bf);
  cvt(down_w, wbf, (long)HS_SZ*INTER_SZ);
  gemm256_kernel<2><<<dim3(16,16), 512, 0, stream>>>(g_bf, wbf, M_TOT, HS_SZ, INTER_SZ,
                                                     nullptr, h2_f, nullptr, (float*)d_out);
}

// Round 4
// 2546.200 us; speedup vs baseline: 1.7430x; 1.1120x over previous
//
#include <hip/hip_runtime.h>
#include <hip/hip_bf16.h>

typedef __attribute__((ext_vector_type(8))) short short8;
typedef __attribute__((ext_vector_type(4))) short short4v;
typedef __attribute__((ext_vector_type(4))) float floatx4;

#define B_SZ 2
#define S_SZ 2048
#define HS_SZ 4096
#define NH_SZ 32
#define HD_SZ 128
#define INTER_SZ 11008
#define M_TOT 4096

__device__ __forceinline__ float b2f(short s){
  unsigned int u = ((unsigned int)(unsigned short)s) << 16;
  return __builtin_bit_cast(float, u);
}
__device__ __forceinline__ short f2b(float f){
  unsigned int u = __builtin_bit_cast(unsigned int, f);
  u = (u + 0x7FFFu + ((u >> 16) & 1u)) >> 16;
  return (short)u;
}

typedef __attribute__((address_space(1))) const unsigned int gu32;
typedef __attribute__((address_space(3))) unsigned int lu32;
__device__ __forceinline__ void gl2lds16(const short* g, short* l){
  __builtin_amdgcn_global_load_lds((gu32*)g, (lu32*)l, 16, 0, 0);
}

#define BARRIER() asm volatile("s_barrier" ::: "memory")
#define WAITV8()  asm volatile("s_waitcnt vmcnt(8)" ::: "memory")
#define WAITV0()  asm volatile("s_waitcnt vmcnt(0)" ::: "memory")

// ---------------- f32 -> bf16 convert (weights) ----------------
__global__ void cvt_bf16_kernel(const float* __restrict__ src, short* __restrict__ dst, long n8){
  long idx = (long)blockIdx.x * blockDim.x + threadIdx.x;
  if (idx >= n8) return;
  long e = idx * 8;
  floatx4 v0 = *(const floatx4*)(src + e);
  floatx4 v1 = *(const floatx4*)(src + e + 4);
  short8 o;
  o[0]=f2b(v0[0]); o[1]=f2b(v0[1]); o[2]=f2b(v0[2]); o[3]=f2b(v0[3]);
  o[4]=f2b(v1[0]); o[5]=f2b(v1[1]); o[6]=f2b(v1[2]); o[7]=f2b(v1[3]);
  *(short8*)(dst + e) = o;
}

// ---------------- embedding gather + concat -> X0 bf16 [M, 2*HS] ----------------
__global__ void embed_concat_kernel(const float* __restrict__ hidden,
                                    const int* __restrict__ ids,
                                    const float* __restrict__ embed,
                                    short* __restrict__ X0){
  long idx = (long)blockIdx.x * blockDim.x + threadIdx.x;
  const long total = (long)M_TOT * (2*HS_SZ) / 4;
  if (idx >= total) return;
  long e = idx * 4;
  int m = (int)(e / (2*HS_SZ));
  int c = (int)(e % (2*HS_SZ));
  const float* src;
  if (c < HS_SZ){
    src = embed + (long)ids[m]*HS_SZ + c;
  } else {
    src = hidden + (long)m*HS_SZ + (c - HS_SZ);
  }
  floatx4 v = *(const floatx4*)src;
  short4v o;
  o[0]=f2b(v[0]); o[1]=f2b(v[1]); o[2]=f2b(v[2]); o[3]=f2b(v[3]);
  *(short4v*)(X0 + e) = o;
}

// ---------------- 256x256 deep-pipelined NT GEMM (unchanged from R3) ----------------
template<int EPI>
__global__ __launch_bounds__(512, 2)
void gemm256_kernel(const short* __restrict__ A, const short* __restrict__ Bw,
                    int M, int N, int K,
                    const float* __restrict__ bias,
                    const float* __restrict__ resid,
                    short* __restrict__ Cbf,
                    float* __restrict__ Cf){
  __shared__ __align__(16) short lds[65536];
  const int tid = threadIdx.x;
  const int wid = tid >> 6;
  const int lane = tid & 63;
  const int wr = wid >> 2, wc = wid & 3;
  const int lr = lane & 15, lk = lane >> 4;
  const int lr7 = lr & 7;

  const int nwg = gridDim.x * gridDim.y;
  const int id  = blockIdx.y * gridDim.x + blockIdx.x;
  const int cpx = nwg >> 3;
  const int sw  = (id & 7) * cpx + (id >> 3);
  const int bx  = sw % gridDim.x;
  const int by  = sw / gridDim.x;
  const int m0 = bx * 256, n0 = by * 256;

  const int srow = lane >> 3;
  const int sslot = (lane & 7) ^ srow;
  const short* gsrc[8];
  int ldsoff[8];
  #pragma unroll
  for (int op=0; op<2; op++)
    #pragma unroll
    for (int h=0; h<2; h++)
      #pragma unroll
      for (int i=0; i<2; i++){
        const int u = op*4 + h*2 + i;
        const int seg = wid*2 + i;
        const int row = (op ? n0 : m0) + h*128 + seg*8 + srow;
        gsrc[u] = (op ? Bw : A) + (long)row*K + sslot*8;
        ldsoff[u] = op*16384 + h*8192 + seg*512;
      }

  floatx4 acc[8][4] = {};
  int a_base[8], b_base[4];
  #pragma unroll
  for (int mf=0; mf<8; mf++) a_base[mf] = (wr*128 + mf*16 + lr)*64;
  #pragma unroll
  for (int nf=0; nf<4; nf++) b_base[nf] = 16384 + (wc*64 + nf*16 + lr)*64;
  const int kslot[2] = { ((0*4+lk)^lr7)*8, ((1*4+lk)^lr7)*8 };

  const int nt = K >> 6;

  #pragma unroll
  for (int u=0; u<8; u++) gl2lds16(gsrc[u], lds + ldsoff[u]);

  for (int t=0; t<nt; ++t){
    const int dbase = (t & 1) * 32768;
    const int nbase = ((t+1) & 1) * 32768;
    if (t+1 < nt){
      const long kn = (long)(t+1) * 64;
      #pragma unroll
      for (int u=0; u<8; u++) gl2lds16(gsrc[u] + kn, lds + nbase + ldsoff[u]);
      WAITV8();
    } else {
      WAITV0();
    }
    BARRIER();
    short8 bfr[4][2];
    #pragma unroll
    for (int q=0; q<4; q++){
      short8 af[2][2];
      #pragma unroll
      for (int p=0; p<2; p++){
        const int ab = dbase + a_base[q*2+p];
        af[p][0] = *(const short8*)(lds + ab + kslot[0]);
        af[p][1] = *(const short8*)(lds + ab + kslot[1]);
      }
      if (q == 0){
        #pragma unroll
        for (int nf=0; nf<4; nf++){
          const int bb = dbase + b_base[nf];
          bfr[nf][0] = *(const short8*)(lds + bb + kslot[0]);
          bfr[nf][1] = *(const short8*)(lds + bb + kslot[1]);
        }
      }
      __builtin_amdgcn_s_setprio(1);
      #pragma unroll
      for (int p=0; p<2; p++){
        #pragma unroll
        for (int nf=0; nf<4; nf++){
          acc[q*2+p][nf] = __builtin_amdgcn_mfma_f32_16x16x32_bf16(af[p][0], bfr[nf][0], acc[q*2+p][nf], 0,0,0);
          acc[q*2+p][nf] = __builtin_amdgcn_mfma_f32_16x16x32_bf16(af[p][1], bfr[nf][1], acc[q*2+p][nf], 0,0,0);
        }
      }
      __builtin_amdgcn_s_setprio(0);
    }
    BARRIER();
  }

  #pragma unroll
  for (int mf=0; mf<8; mf++){
    #pragma unroll
    for (int nf=0; nf<4; nf++){
      const int col = n0 + wc*64 + nf*16 + lr;
      float bcol = (EPI==1) ? bias[col] : 0.0f;
      #pragma unroll
      for (int r=0; r<4; r++){
        const int row = m0 + wr*128 + mf*16 + lk*4 + r;
        float v = acc[mf][nf][r] + bcol;
        if (EPI==2) v += resid[(long)row*N + col];
        if (EPI==0 || EPI==1) Cbf[(long)row*N + col] = f2b(v);
        if (EPI==1 || EPI==2) Cf[(long)row*N + col] = v;
      }
    }
  }
}

// ---------------- RoPE in-place on q,k bf16 [M, NH*HD] ----------------
__global__ void rope_kernel(short* __restrict__ q, short* __restrict__ k,
                            const int* __restrict__ pos_ids){
  long idx = (long)blockIdx.x * blockDim.x + threadIdx.x;
  const long total = (long)M_TOT * NH_SZ * (HD_SZ/2);
  if (idx >= total) return;
  int i  = (int)(idx & 63);
  long rh = idx >> 6;
  int h  = (int)(rh & 31);
  int m  = (int)(rh >> 5);
  int s  = m & (S_SZ - 1);
  float p = (float)pos_ids[s];
  const float L2_10000 = 13.28771237954945f;
  float inv = exp2f(-(2.0f*i/(float)HD_SZ) * L2_10000);
  float fr = p * inv;
  float sn, cs;
  sincosf(fr, &sn, &cs);
  long base = (long)m*HS_SZ + h*HD_SZ;
  short* qp = q + base;
  short* kp = k + base;
  float q1=b2f(qp[i]), q2=b2f(qp[i+64]);
  qp[i]    = f2b(q1*cs - q2*sn);
  qp[i+64] = f2b(q2*cs + q1*sn);
  float k1=b2f(kp[i]), k2=b2f(kp[i+64]);
  kp[i]    = f2b(k1*cs - k2*sn);
  kp[i+64] = f2b(k2*cs + k1*sn);
}

// ---------------- V transpose: v_bf [B,S,NH*HD] -> VT [B*NH*HD, S] ----------------
__global__ __launch_bounds__(256)
void vtrans_kernel(const short* __restrict__ V, short* __restrict__ VT){
  __shared__ short tile[64][68];
  const int s0 = blockIdx.x * 64;
  const int d0 = blockIdx.y * 64;
  const int bh = blockIdx.z;
  const int b = bh >> 5, h = bh & 31;
  const int tid = threadIdx.x;
  #pragma unroll
  for (int it=0; it<2; it++){
    int e = (it*256 + tid) * 8;
    int ss = e >> 6, col = e & 63;
    short8 v = *(const short8*)(V + ((long)(b*S_SZ + s0 + ss))*HS_SZ + h*HD_SZ + d0 + col);
    #pragma unroll
    for (int j=0;j<8;j++) tile[ss][col+j] = v[j];
  }
  __syncthreads();
  #pragma unroll
  for (int it=0; it<2; it++){
    int e = (it*256 + tid) * 8;
    int dd = e >> 6, scol = e & 63;
    short8 w;
    #pragma unroll
    for (int j=0;j<8;j++) w[j] = tile[scol+j][dd];
    *(short8*)(VT + ((long)(bh*HD_SZ + d0 + dd))*S_SZ + s0 + scol) = w;
  }
}

// ---------------- causal flash attention v2 ----------------
// KVB=64, K+VT double-buffered via global_load_lds w=16 with pre-swizzled
// source; counted vmcnt; defer-max rescale.  grid (S/64, B*NH), 256 thr.
__global__ __launch_bounds__(256,2)
void attn_kernel(const short* __restrict__ Q, const short* __restrict__ K,
                 const short* __restrict__ VT, short* __restrict__ O){
  constexpr int LPD = 72;
  __shared__ __align__(16) short lds[32768];        // [2 buf][K 8192 | VT 8192]
  __shared__ __align__(16) short p_lds[4][16*LPD];
  const int bh = blockIdx.y;
  const int b = bh >> 5, h = bh & 31;
  const int q0 = blockIdx.x * 64;
  const int tid = threadIdx.x, wid = tid>>6, lane = tid&63;
  const int lr = lane & 15, lk = lane >> 4;
  const float scale = 0.08838834764831845f;

  // hoist Q fragments (A-operand): row=lr, k = t*32 + lk*8
  const short* qbase = Q + ((long)(b*S_SZ + q0 + wid*16))*HS_SZ + h*HD_SZ;
  short8 qf[4];
  #pragma unroll
  for (int t=0;t<4;t++)
    qf[t] = *(const short8*)(qbase + (long)lr*HS_SZ + t*32 + lk*8);

  // staging bases (pre-swizzled global source, linear LDS dest)
  const short* kb[4]; const short* vb[4];
  int kloff[4], vloff[4];
  #pragma unroll
  for (int p=0;p<4;p++){
    const int seg = wid*4 + p;
    const int rowk = seg*4 + (lane >> 4);           // 0..63
    const int slotk = (lane & 15) ^ (rowk & 15);
    kb[p] = K + ((long)(b*S_SZ) + rowk)*HS_SZ + h*HD_SZ + slotk*8;
    kloff[p] = seg*512;
    const int dv = seg*8 + (lane >> 3);             // 0..127
    const int slotv = (lane & 7) ^ (dv & 7);
    vb[p] = VT + ((long)(bh*HD_SZ + dv))*S_SZ + slotv*8;
    vloff[p] = 8192 + seg*512;
  }

  floatx4 oacc[8] = {};
  float m_run[4] = {-1e30f,-1e30f,-1e30f,-1e30f};
  float l_run[4] = {0.f,0.f,0.f,0.f};

  const int nt = blockIdx.x + 1;                    // (q0+64)/64 kv tiles

  // prologue: stage tile 0 into buf 0
  #pragma unroll
  for (int p=0;p<4;p++){
    gl2lds16(kb[p], lds + kloff[p]);
    gl2lds16(vb[p], lds + vloff[p]);
  }

  for (int t=0; t<nt; ++t){
    const int dbase = (t & 1) * 16384;
    const int nbase = ((t+1) & 1) * 16384;
    if (t+1 < nt){
      const long kkn = (long)(t+1)*64*HS_SZ;
      const long vkn = (long)(t+1)*64;
      #pragma unroll
      for (int p=0;p<4;p++){
        gl2lds16(kb[p] + kkn, lds + nbase + kloff[p]);
        gl2lds16(vb[p] + vkn, lds + nbase + vloff[p]);
      }
      WAITV8();
    } else {
      WAITV0();
    }
    BARRIER();
    const int kv0 = t*64;
    // S = Q K^T : per wave 16q x 64kv
    floatx4 sfr[4];
    #pragma unroll
    for (int fn=0; fn<4; fn++){
      floatx4 s = {0.f,0.f,0.f,0.f};
      const int row = fn*16 + lr;
      #pragma unroll
      for (int tq=0; tq<4; tq++){
        short8 kf = *(const short8*)(lds + dbase + row*128 + (((tq*4+lk)^lr)&15)*8);
        s = __builtin_amdgcn_mfma_f32_16x16x32_bf16(qf[tq], kf, s, 0,0,0);
      }
      sfr[fn] = s;
    }
    // masked scores
    float pv[4][4];
    #pragma unroll
    for (int fn=0; fn<4; fn++){
      const int col = kv0 + fn*16 + lr;
      #pragma unroll
      for (int r=0;r<4;r++){
        const int row = q0 + wid*16 + lk*4 + r;
        float sv = sfr[fn][r] * scale;
        pv[fn][r] = (col > row) ? -1e30f : sv;
      }
    }
    // online softmax with defer-max
    float mr4[4];
    int small = 1;
    #pragma unroll
    for (int r=0;r<4;r++){
      float mr = fmaxf(fmaxf(pv[0][r], pv[1][r]), fmaxf(pv[2][r], pv[3][r]));
      mr = fmaxf(mr, __shfl_xor(mr, 1, 16));
      mr = fmaxf(mr, __shfl_xor(mr, 2, 16));
      mr = fmaxf(mr, __shfl_xor(mr, 4, 16));
      mr = fmaxf(mr, __shfl_xor(mr, 8, 16));
      mr4[r] = mr;
      small &= (mr <= m_run[r] + 8.0f) ? 1 : 0;
    }
    const int skip = __all(small);
    float alpha_[4];
    #pragma unroll
    for (int r=0;r<4;r++){
      float mnew = skip ? m_run[r] : fmaxf(m_run[r], mr4[r]);
      alpha_[r] = skip ? 1.0f : __expf(m_run[r] - mnew);
      m_run[r] = mnew;
      float rs = 0.f;
      #pragma unroll
      for (int fn=0; fn<4; fn++){
        float e = __expf(pv[fn][r] - mnew);
        p_lds[wid][(lk*4+r)*LPD + fn*16 + lr] = f2b(e);
        rs += e;
      }
      rs += __shfl_xor(rs, 1, 16);
      rs += __shfl_xor(rs, 2, 16);
      rs += __shfl_xor(rs, 4, 16);
      rs += __shfl_xor(rs, 8, 16);
      l_run[r] = l_run[r]*alpha_[r] + rs;
    }
    if (!skip){
      #pragma unroll
      for (int f=0; f<8; f++){
        #pragma unroll
        for (int r=0;r<4;r++) oacc[f][r] *= alpha_[r];
      }
    }
    // O += P V : A-frag row=lr, k=tp*32+lk*8 ; B-frag from VT tile
    short8 pf[2];
    #pragma unroll
    for (int tp=0; tp<2; tp++)
      pf[tp] = *(const short8*)(&p_lds[wid][lr*LPD + tp*32 + lk*8]);
    #pragma unroll
    for (int f=0; f<8; f++){
      const int vrow = f*16 + lr;
      #pragma unroll
      for (int tp=0; tp<2; tp++){
        short8 vf = *(const short8*)(lds + dbase + 8192 + vrow*64 + (((tp*4+lk)^(lr&7))&7)*8);
        oacc[f] = __builtin_amdgcn_mfma_f32_16x16x32_bf16(pf[tp], vf, oacc[f], 0,0,0);
      }
    }
    BARRIER();
  }
  // normalize + write
  #pragma unroll
  for (int r=0;r<4;r++){
    const float inv = 1.0f / l_run[r];
    const long row = (long)(b*S_SZ + q0 + wid*16 + lk*4 + r);
    #pragma unroll
    for (int f=0; f<8; f++){
      O[row*HS_SZ + h*HD_SZ + f*16 + lr] = f2b(oacc[f][r]*inv);
    }
  }
}

// ---------------- RMSNorm: f32 in -> bf16 out ----------------
__global__ void rmsnorm_kernel(const float* __restrict__ X, const float* __restrict__ W,
                               short* __restrict__ Y){
  const int row = blockIdx.x;
  const float* x = X + (long)row*HS_SZ;
  float ss = 0.f;
  for (int c = threadIdx.x*4; c < HS_SZ; c += 256*4){
    floatx4 v = *(const floatx4*)(x + c);
    ss += v[0]*v[0] + v[1]*v[1] + v[2]*v[2] + v[3]*v[3];
  }
  ss += __shfl_xor(ss, 32); ss += __shfl_xor(ss, 16);
  ss += __shfl_xor(ss, 8);  ss += __shfl_xor(ss, 4);
  ss += __shfl_xor(ss, 2);  ss += __shfl_xor(ss, 1);
  __shared__ float red[4];
  if ((threadIdx.x & 63) == 0) red[threadIdx.x >> 6] = ss;
  __syncthreads();
  ss = red[0] + red[1] + red[2] + red[3];
  const float rs = rsqrtf(ss / (float)HS_SZ + 1e-6f);
  for (int c = threadIdx.x*4; c < HS_SZ; c += 256*4){
    floatx4 v = *(const floatx4*)(x + c);
    floatx4 w = *(const floatx4*)(W + c);
    short4v o;
    o[0]=f2b(v[0]*rs*w[0]); o[1]=f2b(v[1]*rs*w[1]);
    o[2]=f2b(v[2]*rs*w[2]); o[3]=f2b(v[3]*rs*w[3]);
    *(short4v*)(Y + (long)row*HS_SZ + c) = o;
  }
}

// ---------------- act = silu(g) * u (in-place into g) ----------------
__global__ void silu_mul_kernel(short* __restrict__ G, const short* __restrict__ U){
  long idx = (long)blockIdx.x * blockDim.x + threadIdx.x;
  const long total = (long)M_TOT * INTER_SZ / 8;
  if (idx >= total) return;
  long e = idx * 8;
  short8 g = *(short8*)(G + e);
  short8 u = *(const short8*)(U + e);
  short8 o;
  #pragma unroll
  for (int j=0;j<8;j++){
    float gf = b2f(g[j]);
    float uf = b2f(u[j]);
    float s = gf / (1.0f + __expf(-gf));
    o[j] = f2b(s * uf);
  }
  *(short8*)(G + e) = o;
}

extern "C" void kernel_launch(void* const* d_in, const int* in_sizes, int n_in,
                              void* d_out, int out_size, void* d_ws, size_t ws_size,
                              hipStream_t stream){
  (void)in_sizes; (void)n_in; (void)out_size;
  const float* hidden = (const float*)d_in[0];
  const int*   ids    = (const int*)d_in[1];
  const int*   pos    = (const int*)d_in[2];
  const float* embed  = (const float*)d_in[3];
  const float* fc_w   = (const float*)d_in[4];
  const float* fc_b   = (const float*)d_in[5];
  const float* q_w    = (const float*)d_in[6];
  const float* k_w    = (const float*)d_in[7];
  const float* v_w    = (const float*)d_in[8];
  const float* o_w    = (const float*)d_in[9];
  const float* gate_w = (const float*)d_in[10];
  const float* up_w   = (const float*)d_in[11];
  const float* down_w = (const float*)d_in[12];
  const float* ln_w   = (const float*)d_in[13];

  char* ws = (char*)d_ws;
  size_t off = 0;
  auto alloc = [&](size_t bytes)->char*{
    char* p = ws + off;
    off = (off + bytes + 255) & ~(size_t)255;
    return p;
  };
  short* wbf  = (short*)alloc((size_t)INTER_SZ*HS_SZ*2);
  short* X0   = (short*)alloc((size_t)M_TOT*2*HS_SZ*2);
  short* h_bf = (short*)alloc((size_t)M_TOT*HS_SZ*2);
  float* h_f  = (float*)alloc((size_t)M_TOT*HS_SZ*4);
  short* q_bf = (short*)alloc((size_t)M_TOT*HS_SZ*2);
  short* k_bf = (short*)alloc((size_t)M_TOT*HS_SZ*2);
  short* v_bf = (short*)alloc((size_t)M_TOT*HS_SZ*2);
  short* vt_bf= (short*)alloc((size_t)M_TOT*HS_SZ*2);
  short* a_bf = (short*)alloc((size_t)M_TOT*HS_SZ*2);
  float* h2_f = (float*)alloc((size_t)M_TOT*HS_SZ*4);
  short* hn_bf= (short*)alloc((size_t)M_TOT*HS_SZ*2);
  short* g_bf = (short*)alloc((size_t)M_TOT*INTER_SZ*2);
  short* u_bf = (short*)alloc((size_t)M_TOT*INTER_SZ*2);
  if (ws_size < off) return;

  auto cvt = [&](const float* src, short* dst, long n){
    long n8 = n / 8;
    cvt_bf16_kernel<<<(int)((n8 + 255)/256), 256, 0, stream>>>(src, dst, n8);
  };

  embed_concat_kernel<<<32768, 256, 0, stream>>>(hidden, ids, embed, X0);

  cvt(fc_w, wbf, (long)HS_SZ*2*HS_SZ);
  gemm256_kernel<1><<<dim3(16,16), 512, 0, stream>>>(X0, wbf, M_TOT, HS_SZ, 2*HS_SZ,
                                                     fc_b, nullptr, h_bf, h_f);
  cvt(q_w, wbf, (long)HS_SZ*HS_SZ);
  gemm256_kernel<0><<<dim3(16,16), 512, 0, stream>>>(h_bf, wbf, M_TOT, HS_SZ, HS_SZ,
                                                     nullptr, nullptr, q_bf, nullptr);
  cvt(k_w, wbf, (long)HS_SZ*HS_SZ);
  gemm256_kernel<0><<<dim3(16,16), 512, 0, stream>>>(h_bf, wbf, M_TOT, HS_SZ, HS_SZ,
                                                     nullptr, nullptr, k_bf, nullptr);
  cvt(v_w, wbf, (long)HS_SZ*HS_SZ);
  gemm256_kernel<0><<<dim3(16,16), 512, 0, stream>>>(h_bf, wbf, M_TOT, HS_SZ, HS_SZ,
                                                     nullptr, nullptr, v_bf, nullptr);
  rope_kernel<<<32768, 256, 0, stream>>>(q_bf, k_bf, pos);
  vtrans_kernel<<<dim3(S_SZ/64, HD_SZ/64, B_SZ*NH_SZ), 256, 0, stream>>>(v_bf, vt_bf);
  attn_kernel<<<dim3(S_SZ/64, B_SZ*NH_SZ), 256, 0, stream>>>(q_bf, k_bf, vt_bf, a_bf);
  cvt(o_w, wbf, (long)HS_SZ*HS_SZ);
  gemm256_kernel<2><<<dim3(16,16), 512, 0, stream>>>(a_bf, wbf, M_TOT, HS_SZ, HS_SZ,
                                                     nullptr, h_f, nullptr, h2_f);
  rmsnorm_kernel<<<M_TOT, 256, 0, stream>>>(h2_f, ln_w, hn_bf);
  cvt(gate_w, wbf, (long)INTER_SZ*HS_SZ);
  gemm256_kernel<0><<<dim3(16,43), 512, 0, stream>>>(hn_bf, wbf, M_TOT, INTER_SZ, HS_SZ,
                                                     nullptr, nullptr, g_bf, nullptr);
  cvt(up_w, wbf, (long)INTER_SZ*HS_SZ);
  gemm256_kernel<0><<<dim3(16,43), 512, 0, stream>>>(hn_bf, wbf, M_TOT, INTER_SZ, HS_SZ,
                                                     nullptr, nullptr, u_bf, nullptr);
  silu_mul_kernel<<<22016, 256, 0, stream>>>(g_bf, u_bf);
  cvt(down_w, wbf, (long)HS_SZ*INTER_SZ);
  gemm256_kernel<2><<<dim3(16,16), 512, 0, stream>>>(g_bf, wbf, M_TOT, HS_SZ, INTER_SZ,
                                                     nullptr, h2_f, nullptr, (float*)d_out);
}